// Round 2
// baseline (25.290 us; speedup 1.0000x reference)
//
#include <hip/hip_runtime.h>
#include <math.h>

// Problem constants (match reference)
constexpr int S = 4096;
constexpr int WPB = 4;                 // waves per block (one row per wave)
constexpr int THREADS = 64 * WPB;
constexpr int ITERS = S / (4 * 64);    // 16 int4 loads per lane per row

__global__ __launch_bounds__(THREADS)
void cca_kernel(const float* __restrict__ drowsy,
                const int* __restrict__ gest,
                float* __restrict__ out, int B) {
    const int lane = threadIdx.x & 63;
    const int row = blockIdx.x * WPB + (threadIdx.x >> 6);
    if (row >= B) return;

    const int4* g4 = reinterpret_cast<const int4*>(gest + (size_t)row * S);

    int cnt = 0;   // number of ones in the row (-> max_eye)
    int last = -1; // last index with g == 1 (-> pos)

    #pragma unroll
    for (int k = 0; k < ITERS; ++k) {
        const int idx4 = k * 64 + lane;        // coalesced: wave covers 1 KiB/round
        const int4 v = g4[idx4];
        const int base = idx4 * 4;
        cnt += v.x + v.y + v.z + v.w;
        // values are 0/1, ascending index order => later assignment = larger idx
        if (v.x) last = base;
        if (v.y) last = base + 1;
        if (v.z) last = base + 2;
        if (v.w) last = base + 3;
    }

    // wave-level butterfly reduction (64 lanes), no LDS / no syncthreads
    #pragma unroll
    for (int m = 32; m >= 1; m >>= 1) {
        cnt += __shfl_xor(cnt, m, 64);
        last = max(last, __shfl_xor(last, m, 64));
    }

    if (lane == 0) {
        const int pos = (last >= 0) ? last : 0;   // argmax of all-zero row is 0

        // max_eye = cnt; max_att = S-1-pos (finite iff pos < S-1)
        float adjustment = 0.0f;
        if (cnt >= 40 && pos <= S - 1 - 40) {     // max_eye>=40 && max_att>=40
            const float excess = (float)(S - 1 - pos) - 40.0f;  // >= 0 here
            adjustment = 0.05f * (1.0f - expf(-excess * (3.0f / 160.0f)));
        }
        float r = drowsy[row] * (1.0f - adjustment);
        out[row] = fminf(fmaxf(r, 0.01f), 1.0f);
    }
}

extern "C" void kernel_launch(void* const* d_in, const int* in_sizes, int n_in,
                              void* d_out, int out_size, void* d_ws, size_t ws_size,
                              hipStream_t stream) {
    const float* drowsy = (const float*)d_in[0]; // [B,1] float32
    const int* gest = (const int*)d_in[1];       // [B,S,1] int32
    float* out = (float*)d_out;                  // [B,1] float32
    const int B = in_sizes[0];                   // 8192

    const int grid = (B + WPB - 1) / WPB;        // 2048 blocks, 4 rows each
    cca_kernel<<<grid, THREADS, 0, stream>>>(drowsy, gest, out, B);
}